// Round 6
// baseline (1926.629 us; speedup 1.0000x reference)
//
#include <hip/hip_runtime.h>
#include <hip/hip_fp16.h>

#define B_ 256
#define T_ 1200
#define I_ 16
#define H_ 128
#define NT_ (T_ / 8)   // 150 h0-tiles of 8 timesteps (KB staging)

typedef __attribute__((ext_vector_type(2))) _Float16 h2;
typedef __attribute__((ext_vector_type(8))) _Float16 f16x8;

union f16x8u { f16x8 v; h2 h[4]; _Float16 s[8]; };

#if __has_builtin(__builtin_amdgcn_fdot2)
__device__ __forceinline__ float fdot2(h2 a, h2 b, float c) {
  return __builtin_amdgcn_fdot2(a, b, c, false);  // v_dot2_f32_f16
}
#else
__device__ __forceinline__ float fdot2(h2 a, h2 b, float c) {
  return fmaf((float)a.x, (float)b.x, fmaf((float)a.y, (float)b.y, c));
}
#endif

// broadcast one quad lane to all 4 (DPP quad_perm). PAT compile-time const.
template <int PAT>
__device__ __forceinline__ float qbcast(float x) {
  return __int_as_float(__builtin_amdgcn_update_dpp(0, __float_as_int(x), PAT, 0xF, 0xF, true));
}

// reduce quad-uniform values across the 16 quads of a wave
__device__ __forceinline__ float wred(float x) {
  x += __int_as_float(__builtin_amdgcn_update_dpp(0, __float_as_int(x), 0x141, 0xF, 0xF, true)); // row_half_mirror ~ xor4
  x += __int_as_float(__builtin_amdgcn_update_dpp(0, __float_as_int(x), 0x140, 0xF, 0xF, true)); // row_mirror ~ xor8
  x += __shfl_xor(x, 16);
  x += __shfl_xor(x, 32);
  return x;
}

__device__ __forceinline__ float sigm(float x) {
  return __builtin_amdgcn_rcpf(1.f + __expf(-x));
}
__device__ __forceinline__ float tanh_(float x) {
  return 1.f - 2.f * __builtin_amdgcn_rcpf(1.f + __expf(2.f * x));
}

// Load a 128-wide f32 weight row as 64 fp16x2 into regs.
__device__ __forceinline__ void load_row_h2(const float* __restrict__ p, h2* w) {
#pragma unroll
  for (int i = 0; i < 32; ++i) {
    const float4 v = *(const float4*)(p + 4 * i);
    w[2 * i].x     = (_Float16)v.x; w[2 * i].y     = (_Float16)v.y;
    w[2 * i + 1].x = (_Float16)v.z; w[2 * i + 1].y = (_Float16)v.w;
  }
}

// ---------------------------------------------------------------------------
// K1: layer-0 recurrence. 1 block per batch row, 512 thr.
// Thread owns gate-row g = q*128 + j: full-row dot, no cross-lane reduce.
// Weights 64+8 h2 in regs (fits the 128-reg cap -> no scratch/AGPR shuffle).
// x[b] staged once in LDS fp16 (38.4 KB). 1 barrier/step. Gates gathered via
// quad_perm broadcasts (quad lane index == gate index). Branch-free per-lane
// activation: act = s0 + s1 * rcp(1 + exp(s2*pre)) (sigm or tanh by q).
// Writes h0[b,t,:] fp16 to workspace.
// ---------------------------------------------------------------------------
__global__ __launch_bounds__(512, 2) void k1_layer0(
    const float* __restrict__ xin,
    const float* __restrict__ Wih0, const float* __restrict__ Whh0,
    const float* __restrict__ bih0, const float* __restrict__ bhh0,
    __half* __restrict__ h0ws)
{
  __shared__ __align__(16) __half xs[T_ * I_];   // 38400 B
  __shared__ __align__(16) __half hb[2][H_];

  const int tid = threadIdx.x;
  const int q = tid & 3;
  const int j = tid >> 2;
  const int g = q * H_ + j;
  const int b = blockIdx.x;

  // stage x[b] -> LDS fp16 (coalesced float4 reads)
  {
    const float4* xg4 = (const float4*)(xin + (size_t)b * T_ * I_);
    for (int idx = tid; idx < T_ * I_ / 4; idx += 512) {
      const float4 v = xg4[idx];
      xs[4 * idx]     = __float2half(v.x);
      xs[4 * idx + 1] = __float2half(v.y);
      xs[4 * idx + 2] = __float2half(v.z);
      xs[4 * idx + 3] = __float2half(v.w);
    }
  }

  h2 wh[64], wx[8];
  load_row_h2(Whh0 + (size_t)g * H_, wh);
  {
    const float* px = Wih0 + (size_t)g * I_;
#pragma unroll
    for (int i = 0; i < 4; ++i) {
      const float4 v = *(const float4*)(px + 4 * i);
      wx[2 * i].x     = (_Float16)v.x; wx[2 * i].y     = (_Float16)v.y;
      wx[2 * i + 1].x = (_Float16)v.z; wx[2 * i + 1].y = (_Float16)v.w;
    }
  }
  const float bs = bih0[g] + bhh0[g];
  // per-lane activation constants: q==2 -> tanh, else sigmoid
  const float s0 = (q == 2) ? 1.f : 0.f;
  const float s1 = (q == 2) ? -2.f : 1.f;
  const float s2 = (q == 2) ? 2.f : -1.f;

  if (tid < H_) hb[0][tid] = __float2half(0.f);
  float cst = 0.f;
  __half* h0o = h0ws + (size_t)b * T_ * H_ + j;
  __syncthreads();

#pragma unroll 2
  for (int t = 0; t < T_; ++t) {
    const int rb = t & 1;
    float a0 = 0.f, a1 = 0.f, a2 = 0.f, a3 = 0.f;
#pragma unroll
    for (int i = 0; i < 16; ++i) {                       // h_{t-1} dot (broadcast)
      f16x8u u; u.v = *(const f16x8*)(&hb[rb][8 * i]);
      a0 = fdot2(wh[4 * i],     u.h[0], a0);
      a1 = fdot2(wh[4 * i + 1], u.h[1], a1);
      a2 = fdot2(wh[4 * i + 2], u.h[2], a2);
      a3 = fdot2(wh[4 * i + 3], u.h[3], a3);
    }
#pragma unroll
    for (int m = 0; m < 2; ++m) {                        // x_t dot
      f16x8u u; u.v = *(const f16x8*)(&xs[t * I_ + 8 * m]);
      a0 = fdot2(wx[4 * m],     u.h[0], a0);
      a1 = fdot2(wx[4 * m + 1], u.h[1], a1);
      a2 = fdot2(wx[4 * m + 2], u.h[2], a2);
      a3 = fdot2(wx[4 * m + 3], u.h[3], a3);
    }
    const float pre = (a0 + a1) + (a2 + a3) + bs;        // this thread's gate q
    const float act = fmaf(s1, __builtin_amdgcn_rcpf(1.f + __expf(s2 * pre)), s0);
    const float ig = qbcast<0x00>(act);
    const float fg = qbcast<0x55>(act);
    const float gg = qbcast<0xAA>(act);
    const float og = qbcast<0xFF>(act);
    cst = fg * cst + ig * gg;
    const float hv = og * tanh_(cst);
    const __half hh = __float2half(hv);
    if (q == 0) {
      hb[rb ^ 1][j] = hh;
      h0o[(size_t)t * H_] = hh;
    }
    __syncthreads();
  }
}

// ---------------------------------------------------------------------------
// KB: layer-1 recurrence + relu + W_lin head, producer/consumer wave groups.
// 1 block per batch row, 1024 thr. Group A (tid<512) holds W_ih1 row g in
// regs and computes aih[t+1] = W_ih1 . h0_{t+1} ONE STEP AHEAD of group B
// (tid>=512), which holds W_hh1 row g, consumes aih[t] + h1_{t-1} and runs
// the cell + fused head. ONE barrier/step covers both handoffs.
// h0 is staged global->LDS in 8-step tiles, double buffered (load issued at
// window start, LDS-written at window step 6, consumed from step 7 on).
// Per-thread weights = 64 h2 -> fits 128-reg cap, no scratch.
// ---------------------------------------------------------------------------
__global__ __attribute__((amdgpu_waves_per_eu(4, 4)))
__launch_bounds__(1024) void kb_layer1(
    const __half* __restrict__ h0ws,
    const float* __restrict__ Wih1, const float* __restrict__ Whh1,
    const float* __restrict__ bih1, const float* __restrict__ bhh1,
    const float* __restrict__ Wlin, const float* __restrict__ blin,
    float* __restrict__ out)
{
  __shared__ __align__(16) __half h0til[2][8 * H_];  // 2 x 2 KB tile
  __shared__ __align__(16) float aih[2][512];        // A->B gate pre-sums
  __shared__ __align__(16) __half h1b[2][H_];
  __shared__ __align__(16) float red[2][8];

  const int tid = threadIdx.x;
  const bool isA = tid < 512;
  const int lid = tid & 511;
  const int q = lid & 3;
  const int j = lid >> 2;
  const int g = q * H_ + j;
  const int b = blockIdx.x;

  h2 w[64];
  load_row_h2((isA ? Wih1 : Whh1) + (size_t)g * H_, w);

  // B-only parameters (harmless for A)
  const float bs = bih1[g] + bhh1[g];
  const float wl = Wlin[j];
  const float bl = blin[0];
  const float s0 = (q == 2) ? 1.f : 0.f;
  const float s1 = (q == 2) ? -2.f : 1.f;
  const float s2 = (q == 2) ? 2.f : -1.f;

  const uint* h0u = (const uint*)(h0ws + (size_t)b * T_ * H_);  // u32 view

  // ---- prologue: stage tile 0, compute aih[0], init h1 state ----
  if (isA) ((uint*)h0til[0])[lid] = h0u[lid];
  if (!isA && lid < H_) h1b[0][lid] = __float2half(0.f);
  __syncthreads();
  if (isA) {
    float a0 = 0.f, a1 = 0.f, a2 = 0.f, a3 = 0.f;
#pragma unroll
    for (int i = 0; i < 16; ++i) {
      f16x8u u; u.v = *(const f16x8*)(&h0til[0][8 * i]);
      a0 = fdot2(w[4 * i],     u.h[0], a0);
      a1 = fdot2(w[4 * i + 1], u.h[1], a1);
      a2 = fdot2(w[4 * i + 2], u.h[2], a2);
      a3 = fdot2(w[4 * i + 3], u.h[3], a3);
    }
    aih[0][lid] = (a0 + a1) + (a2 + a3);
  }
  __syncthreads();

  float cst = 0.f;
  uint stg = 0;
  float* op = out + (size_t)b * T_;

  for (int t = 0; t < T_; ++t) {
    const int rb = t & 1;
    if (isA) {
      // stage-issue: at window start t=8m, fetch tile m+1 (1 u32/thread)
      if ((t & 7) == 0) {
        const int m1 = (t >> 3) + 1;
        if (m1 < NT_) stg = h0u[m1 * 512 + lid];
      }
      const int tt = t + 1;
      if (tt < T_) {
        const __half* hsrc = &h0til[(tt >> 3) & 1][(tt & 7) * H_];
        float a0 = 0.f, a1 = 0.f, a2 = 0.f, a3 = 0.f;
#pragma unroll
        for (int i = 0; i < 16; ++i) {
          f16x8u u; u.v = *(const f16x8*)(hsrc + 8 * i);
          a0 = fdot2(w[4 * i],     u.h[0], a0);
          a1 = fdot2(w[4 * i + 1], u.h[1], a1);
          a2 = fdot2(w[4 * i + 2], u.h[2], a2);
          a3 = fdot2(w[4 * i + 3], u.h[3], a3);
        }
        aih[tt & 1][lid] = (a0 + a1) + (a2 + a3);
      }
      // stage-write: at t=8m+6, LDS-write tile m+1 (read starts t=8m+7)
      if ((t & 7) == 6) {
        const int m1 = (t >> 3) + 1;
        if (m1 < NT_) ((uint*)h0til[m1 & 1])[lid] = stg;
      }
    } else {
      float a0 = 0.f, a1 = 0.f, a2 = 0.f, a3 = 0.f;
#pragma unroll
      for (int i = 0; i < 16; ++i) {                     // h1_{t-1} dot
        f16x8u u; u.v = *(const f16x8*)(&h1b[rb][8 * i]);
        a0 = fdot2(w[4 * i],     u.h[0], a0);
        a1 = fdot2(w[4 * i + 1], u.h[1], a1);
        a2 = fdot2(w[4 * i + 2], u.h[2], a2);
        a3 = fdot2(w[4 * i + 3], u.h[3], a3);
      }
      const float pre = (a0 + a1) + (a2 + a3) + aih[rb][lid] + bs;
      const float act = fmaf(s1, __builtin_amdgcn_rcpf(1.f + __expf(s2 * pre)), s0);
      const float ig = qbcast<0x00>(act);
      const float fg = qbcast<0x55>(act);
      const float gg = qbcast<0xAA>(act);
      const float og = qbcast<0xFF>(act);
      cst = fg * cst + ig * gg;
      const float hv = og * tanh_(cst);
      if (q == 0) h1b[rb ^ 1][j] = __float2half(hv);
      // head: relu + W_lin (quad-uniform -> wred over B's 16 quads/wave)
      const float val = wred(fmaxf(hv, 0.f) * wl);
      if ((lid & 63) == 0) red[rb][lid >> 6] = val;
      // straggler (rotating) outputs t-1 from the buffer written last step
      if (t > 0 && lid == (((t - 1) & 7) << 6)) {
        const float4 r0 = *(const float4*)(&red[rb ^ 1][0]);
        const float4 r1 = *(const float4*)(&red[rb ^ 1][4]);
        op[t - 1] = bl + r0.x + r0.y + r0.z + r0.w + r1.x + r1.y + r1.z + r1.w;
      }
    }
    __syncthreads();
  }
  // epilogue: emit t = T-1
  if (!isA && lid == (((T_ - 1) & 7) << 6)) {
    const float4 r0 = *(const float4*)(&red[(T_ - 1) & 1][0]);
    const float4 r1 = *(const float4*)(&red[(T_ - 1) & 1][4]);
    op[T_ - 1] = bl + r0.x + r0.y + r0.z + r0.w + r1.x + r1.y + r1.z + r1.w;
  }
}

// ---------------------------------------------------------------------------
// Fallback: round-1 fused kernel (known-good, 1751 us) if workspace is small.
// ---------------------------------------------------------------------------
__device__ __forceinline__ float qsum8f(float x) {
  x += __int_as_float(__builtin_amdgcn_update_dpp(0, __float_as_int(x), 0xB1, 0xF, 0xF, true));
  x += __int_as_float(__builtin_amdgcn_update_dpp(0, __float_as_int(x), 0x4E, 0xF, 0xF, true));
  return x;
}

__global__ __launch_bounds__(512, 2) void lstm_fused_fb(
    const float* __restrict__ xin,
    const float* __restrict__ Wih0, const float* __restrict__ Whh0,
    const float* __restrict__ bih0, const float* __restrict__ bhh0,
    const float* __restrict__ Wih1, const float* __restrict__ Whh1,
    const float* __restrict__ bih1, const float* __restrict__ bhh1,
    const float* __restrict__ Wlin, const float* __restrict__ blin,
    float* __restrict__ out)
{
  __shared__ __align__(16) __half buf0[2][H_];
  __shared__ __align__(16) __half buf1[2][H_];
  __shared__ __align__(16) float red[2][8];

  const int tid = threadIdx.x;
  const int c = tid & 3;
  const int j = tid >> 2;
  const int b = blockIdx.x;
  const int wv = tid >> 6;

  h2 w0[4][16], wi[4][16], wh[4][16];
  h2 wx[4][2];
  float bs0[4], bs1[4];

#pragma unroll
  for (int qq = 0; qq < 4; ++qq) {
    const int g = qq * H_ + j;
    const float* p0 = Whh0 + (size_t)g * H_ + c * 32;
    const float* p1 = Wih1 + (size_t)g * H_ + c * 32;
    const float* p2 = Whh1 + (size_t)g * H_ + c * 32;
#pragma unroll
    for (int i = 0; i < 8; ++i) {
      float4 v = *(const float4*)(p0 + 4 * i);
      w0[qq][2*i].x   = (_Float16)v.x; w0[qq][2*i].y   = (_Float16)v.y;
      w0[qq][2*i+1].x = (_Float16)v.z; w0[qq][2*i+1].y = (_Float16)v.w;
      v = *(const float4*)(p1 + 4 * i);
      wi[qq][2*i].x   = (_Float16)v.x; wi[qq][2*i].y   = (_Float16)v.y;
      wi[qq][2*i+1].x = (_Float16)v.z; wi[qq][2*i+1].y = (_Float16)v.w;
      v = *(const float4*)(p2 + 4 * i);
      wh[qq][2*i].x   = (_Float16)v.x; wh[qq][2*i].y   = (_Float16)v.y;
      wh[qq][2*i+1].x = (_Float16)v.z; wh[qq][2*i+1].y = (_Float16)v.w;
    }
    const float4 vx = *(const float4*)(Wih0 + (size_t)g * I_ + 4 * c);
    wx[qq][0].x = (_Float16)vx.x; wx[qq][0].y = (_Float16)vx.y;
    wx[qq][1].x = (_Float16)vx.z; wx[qq][1].y = (_Float16)vx.w;
    bs0[qq] = bih0[g] + bhh0[g];
    bs1[qq] = bih1[g] + bhh1[g];
  }
  const float wl = Wlin[j];
  const float bl = blin[0];

  if (tid < H_) {
    buf0[0][tid] = __float2half(0.f);
    buf1[0][tid] = __float2half(0.f);
  }
  float cst0 = 0.f, cst1 = 0.f;
  const float* xp = xin + (size_t)b * T_ * I_ + 4 * c;
  float* op = out + (size_t)b * T_;
  __syncthreads();

#pragma unroll 2
  for (int t = 0; t < T_; ++t) {
    const int rb = t & 1;
    const float4 xv = *(const float4*)xp; xp += I_;
    float a0 = 0.f, a1 = 0.f, a2 = 0.f, a3 = 0.f;
#pragma unroll
    for (int i = 0; i < 4; ++i) {
      f16x8u u; u.v = *(const f16x8*)(&buf0[rb][c * 32 + i * 8]);
#pragma unroll
      for (int p = 0; p < 4; ++p) {
        const h2 hv = u.h[p];
        a0 = fdot2(w0[0][4 * i + p], hv, a0);
        a1 = fdot2(w0[1][4 * i + p], hv, a1);
        a2 = fdot2(w0[2][4 * i + p], hv, a2);
        a3 = fdot2(w0[3][4 * i + p], hv, a3);
      }
    }
    h2 xa, xb;
    xa.x = (_Float16)xv.x; xa.y = (_Float16)xv.y;
    xb.x = (_Float16)xv.z; xb.y = (_Float16)xv.w;
    a0 = fdot2(wx[0][0], xa, fdot2(wx[0][1], xb, a0));
    a1 = fdot2(wx[1][0], xa, fdot2(wx[1][1], xb, a1));
    a2 = fdot2(wx[2][0], xa, fdot2(wx[2][1], xb, a2));
    a3 = fdot2(wx[3][0], xa, fdot2(wx[3][1], xb, a3));
    {
      const float g0 = qsum8f(a0) + bs0[0];
      const float g1 = qsum8f(a1) + bs0[1];
      const float g2 = qsum8f(a2) + bs0[2];
      const float g3 = qsum8f(a3) + bs0[3];
      const float ig = sigm(g0), fg = sigm(g1), gg = tanh_(g2), og = sigm(g3);
      cst0 = fg * cst0 + ig * gg;
      const float h0v = og * tanh_(cst0);
      if (c == 0) buf0[rb ^ 1][j] = __float2half(h0v);
    }
    __syncthreads();
    a0 = 0.f; a1 = 0.f; a2 = 0.f; a3 = 0.f;
#pragma unroll
    for (int i = 0; i < 4; ++i) {
      f16x8u u; u.v = *(const f16x8*)(&buf0[rb ^ 1][c * 32 + i * 8]);
#pragma unroll
      for (int p = 0; p < 4; ++p) {
        const h2 hv = u.h[p];
        a0 = fdot2(wi[0][4 * i + p], hv, a0);
        a1 = fdot2(wi[1][4 * i + p], hv, a1);
        a2 = fdot2(wi[2][4 * i + p], hv, a2);
        a3 = fdot2(wi[3][4 * i + p], hv, a3);
      }
    }
#pragma unroll
    for (int i = 0; i < 4; ++i) {
      f16x8u u; u.v = *(const f16x8*)(&buf1[rb][c * 32 + i * 8]);
#pragma unroll
      for (int p = 0; p < 4; ++p) {
        const h2 hv = u.h[p];
        a0 = fdot2(wh[0][4 * i + p], hv, a0);
        a1 = fdot2(wh[1][4 * i + p], hv, a1);
        a2 = fdot2(wh[2][4 * i + p], hv, a2);
        a3 = fdot2(wh[3][4 * i + p], hv, a3);
      }
    }
    const float g0 = qsum8f(a0) + bs1[0];
    const float g1 = qsum8f(a1) + bs1[1];
    const float g2 = qsum8f(a2) + bs1[2];
    const float g3 = qsum8f(a3) + bs1[3];
    const float ig = sigm(g0), fg = sigm(g1), gg = tanh_(g2), og = sigm(g3);
    cst1 = fg * cst1 + ig * gg;
    const float h1v = og * tanh_(cst1);
    if (c == 0) buf1[rb ^ 1][j] = __float2half(h1v);
    float val = wred(fmaxf(h1v, 0.f) * wl);
    if ((tid & 63) == 0) red[rb][wv] = val;
    __syncthreads();
    if (tid == ((t & 7) << 6)) {
      const float4 r0 = *(const float4*)(&red[rb][0]);
      const float4 r1 = *(const float4*)(&red[rb][4]);
      op[t] = bl + r0.x + r0.y + r0.z + r0.w + r1.x + r1.y + r1.z + r1.w;
    }
  }
}

extern "C" void kernel_launch(void* const* d_in, const int* in_sizes, int n_in,
                              void* d_out, int out_size, void* d_ws, size_t ws_size,
                              hipStream_t stream) {
  const size_t H0_BYTES = (size_t)B_ * T_ * H_ * sizeof(__half);  // 78.6 MB

  if (d_ws != nullptr && ws_size >= H0_BYTES) {
    __half* h0ws = (__half*)d_ws;
    k1_layer0<<<B_, 512, 0, stream>>>(
        (const float*)d_in[0],
        (const float*)d_in[1], (const float*)d_in[2],
        (const float*)d_in[3], (const float*)d_in[4],
        h0ws);
    kb_layer1<<<B_, 1024, 0, stream>>>(
        h0ws,
        (const float*)d_in[5], (const float*)d_in[6],
        (const float*)d_in[7], (const float*)d_in[8],
        (const float*)d_in[9], (const float*)d_in[10],
        (float*)d_out);
  } else {
    lstm_fused_fb<<<B_, 512, 0, stream>>>(
        (const float*)d_in[0],
        (const float*)d_in[1], (const float*)d_in[2],
        (const float*)d_in[3], (const float*)d_in[4],
        (const float*)d_in[5], (const float*)d_in[6],
        (const float*)d_in[7], (const float*)d_in[8],
        (const float*)d_in[9], (const float*)d_in[10],
        (float*)d_out);
  }
}